// Round 19
// baseline (256.782 us; speedup 1.0000x reference)
//
#include <hip/hip_runtime.h>

typedef short s16x8 __attribute__((ext_vector_type(8)));
typedef short s16x4 __attribute__((ext_vector_type(4)));
typedef float f32x4 __attribute__((ext_vector_type(4)));

#define B_   4
#define N_   1024
#define C_   1024
#define H_   16
#define D_   64
#define FFH_ 2730
#define FFP_ 2752

__device__ __forceinline__ short f2bf(float f) {
  unsigned u = __float_as_uint(f);
  u += 0x7fff + ((u >> 16) & 1);           // RNE to bf16
  return (short)(unsigned short)(u >> 16);
}
__device__ __forceinline__ float bf2f(short s) {
  return __uint_as_float(((unsigned)(unsigned short)s) << 16);
}
__device__ __forceinline__ float silu(float x) { return x / (1.f + __expf(-x)); }

// async global->LDS, 16B per lane; LDS dest is wave-uniform base + lane*16
__device__ __forceinline__ void gload16(const void* g, void* l) {
  __builtin_amdgcn_global_load_lds(
      (const __attribute__((address_space(1))) unsigned*)g,
      (__attribute__((address_space(3))) unsigned*)l, 16, 0, 0);
}

// ---------------- weight conversion: qkv + proj + w12 + padded w3, one launch ----------------
__global__ void cvt4(const float* __restrict__ s0, short* __restrict__ d0, const int n0,
                     const float* __restrict__ s1, short* __restrict__ d1, const int n1,
                     const float* __restrict__ s2, short* __restrict__ d2, const int n2,
                     const float* __restrict__ s3, short* __restrict__ d3, const int n3) {
  const int tot = n0 + n1 + n2 + n3;
  for (int i = blockIdx.x * 256 + threadIdx.x; i < tot; i += gridDim.x * 256) {
    int j = i;
    if (j < n0) {
      const float4 v = ((const float4*)s0)[j];
      s16x4 o; o[0] = f2bf(v.x); o[1] = f2bf(v.y); o[2] = f2bf(v.z); o[3] = f2bf(v.w);
      *(s16x4*)(d0 + (size_t)j * 4) = o;
    } else if ((j -= n0) < n1) {
      const float4 v = ((const float4*)s1)[j];
      s16x4 o; o[0] = f2bf(v.x); o[1] = f2bf(v.y); o[2] = f2bf(v.z); o[3] = f2bf(v.w);
      *(s16x4*)(d1 + (size_t)j * 4) = o;
    } else if ((j -= n1) < n2) {
      const float4 v = ((const float4*)s2)[j];
      s16x4 o; o[0] = f2bf(v.x); o[1] = f2bf(v.y); o[2] = f2bf(v.z); o[3] = f2bf(v.w);
      *(s16x4*)(d2 + (size_t)j * 4) = o;
    } else {
      j -= n2;
      const int row = j / (FFP_ / 4);
      const int cb = (j % (FFP_ / 4)) * 4;
      s16x4 o;
      #pragma unroll
      for (int e = 0; e < 4; ++e) {
        const int col = cb + e;
        o[e] = (col < FFH_) ? f2bf(s3[(size_t)row * FFH_ + col]) : (short)0;
      }
      *(s16x4*)(d3 + (size_t)row * FFP_ + cb) = o;
    }
  }
}

// ---------------- ada = silu(c) @ ada_w.T + ada_b ----------------
__global__ void ada_gemm(const float* __restrict__ c, const float* __restrict__ aw,
                         const float* __restrict__ ab, float* __restrict__ ada) {
  const int j = blockIdx.x;
  const int l = threadIdx.x;
  float acc[4] = {0.f, 0.f, 0.f, 0.f};
  const float4* wr = (const float4*)(aw + (size_t)j * 1024);
  #pragma unroll
  for (int p = 0; p < 4; ++p) {
    const float4 wv = wr[p * 64 + l];
    #pragma unroll
    for (int b = 0; b < 4; ++b) {
      const float4 cv = ((const float4*)(c + b * 1024))[p * 64 + l];
      acc[b] += silu(cv.x) * wv.x + silu(cv.y) * wv.y + silu(cv.z) * wv.z + silu(cv.w) * wv.w;
    }
  }
  #pragma unroll
  for (int b = 0; b < 4; ++b) {
    float a = acc[b];
    #pragma unroll
    for (int m = 1; m < 64; m <<= 1) a += __shfl_xor(a, m);
    if (l == 0) ada[b * 6144 + j] = a + ab[j];
  }
}

// ---------------- fused rmsnorm + modulate (fp32 in) -> bf16 ----------------
__global__ void rmsmod(const float* __restrict__ x, const float* __restrict__ wn,
                       const float* __restrict__ ada, const int sOff, const int gOff,
                       short* __restrict__ out) {
  const int row = blockIdx.x;
  const int b = row >> 10;
  const int t = threadIdx.x;
  const float4 v = ((const float4*)(x + (size_t)row * 1024))[t];
  float ss = v.x * v.x + v.y * v.y + v.z * v.z + v.w * v.w;
  #pragma unroll
  for (int m = 1; m < 64; m <<= 1) ss += __shfl_xor(ss, m);
  __shared__ float red[4];
  if ((t & 63) == 0) red[t >> 6] = ss;
  __syncthreads();
  const float rs = rsqrtf((red[0] + red[1] + red[2] + red[3]) * (1.f / 1024.f) + 1e-6f);
  const int j = t * 4;
  const float* sp = ada + b * 6144 + sOff + j;
  const float* gp = ada + b * 6144 + gOff + j;
  s16x4 o;
  o[0] = f2bf(v.x * rs * wn[j + 0] * (1.f + gp[0]) + sp[0]);
  o[1] = f2bf(v.y * rs * wn[j + 1] * (1.f + gp[1]) + sp[1]);
  o[2] = f2bf(v.z * rs * wn[j + 2] * (1.f + gp[2]) + sp[2]);
  o[3] = f2bf(v.w * rs * wn[j + 3] * (1.f + gp[3]) + sp[3]);
  *(s16x4*)(out + (size_t)row * 1024 + j) = o;
}

// ---------------- fused rmsnorm + modulate (bf16 in) -> bf16 ----------------
__global__ void rmsmod_b(const short* __restrict__ x, const float* __restrict__ wn,
                         const float* __restrict__ ada, const int sOff, const int gOff,
                         short* __restrict__ out) {
  const int row = blockIdx.x;
  const int b = row >> 10;
  const int t = threadIdx.x;
  const s16x4 vb = *(const s16x4*)(x + (size_t)row * 1024 + t * 4);
  const float v0 = bf2f(vb[0]), v1 = bf2f(vb[1]), v2 = bf2f(vb[2]), v3 = bf2f(vb[3]);
  float ss = v0 * v0 + v1 * v1 + v2 * v2 + v3 * v3;
  #pragma unroll
  for (int m = 1; m < 64; m <<= 1) ss += __shfl_xor(ss, m);
  __shared__ float red[4];
  if ((t & 63) == 0) red[t >> 6] = ss;
  __syncthreads();
  const float rs = rsqrtf((red[0] + red[1] + red[2] + red[3]) * (1.f / 1024.f) + 1e-6f);
  const int j = t * 4;
  const float* sp = ada + b * 6144 + sOff + j;
  const float* gp = ada + b * 6144 + gOff + j;
  s16x4 o;
  o[0] = f2bf(v0 * rs * wn[j + 0] * (1.f + gp[0]) + sp[0]);
  o[1] = f2bf(v1 * rs * wn[j + 1] * (1.f + gp[1]) + sp[1]);
  o[2] = f2bf(v2 * rs * wn[j + 2] * (1.f + gp[2]) + sp[2]);
  o[3] = f2bf(v3 * rs * wn[j + 3] * (1.f + gp[3]) + sp[3]);
  *(s16x4*)(out + (size_t)row * 1024 + j) = o;
}

// ---------------- qkv GEMM: 128x128 tile, 2-phase dbuf, fused q/k rmsnorm + v ----------------
__launch_bounds__(256, 2)
__global__ void gemm_qkv(const short* __restrict__ A, const short* __restrict__ Bt,
                         const float* __restrict__ bias,
                         short* __restrict__ qbO, short* __restrict__ kbO,
                         short* __restrict__ vrO,
                         const float* __restrict__ qnw, const float* __restrict__ knw) {
  __shared__ short As[2][128 * 64];
  __shared__ short Bs[2][128 * 64];
  const int t = threadIdx.x;
  const int l = t & 63;
  const int w = t >> 6;
  const int wr = (w >> 1) * 64, wc = (w & 1) * 64;
  const int K = 1024;

  const int nwg = gridDim.x * gridDim.y;
  int lin = blockIdx.y * gridDim.x + blockIdx.x;
  lin = (lin & 7) * (nwg >> 3) + (lin >> 3);
  const int m0 = (lin / gridDim.x) * 128;
  const int n0 = (lin % gridDim.x) * 128;

  f32x4 acc[4][4];
  const f32x4 z4 = {0.f, 0.f, 0.f, 0.f};
  #pragma unroll
  for (int i = 0; i < 4; ++i)
    #pragma unroll
    for (int j = 0; j < 4; ++j) acc[i][j] = z4;

  const int lr = l >> 3;
  const int lc = (l & 7) ^ lr;          // pre-swizzled source chunk (rule #21)
  const short* gAs = A + (size_t)(m0 + w * 32 + lr) * K + lc * 8;
  const short* gBs = Bt + (size_t)(n0 + w * 32 + lr) * K + lc * 8;
  const int wofs = (w * 32) * 64;

#define STAGE_Q(buf, kt)                                                       \
  do {                                                                         \
    const int _ko = (kt) * 64;                                                 \
    _Pragma("unroll") for (int p = 0; p < 4; ++p) {                            \
      gload16(gAs + (size_t)p * 8 * K + _ko, &As[buf][wofs + p * 8 * 64]);     \
      gload16(gBs + (size_t)p * 8 * K + _ko, &Bs[buf][wofs + p * 8 * 64]);     \
    }                                                                          \
  } while (0)

  STAGE_Q(0, 0);
  __syncthreads();

  for (int kt = 0; kt < 16; ++kt) {
    const int cur = kt & 1;
    if (kt + 1 < 16) STAGE_Q(cur ^ 1, kt + 1);   // loads in flight during MFMA
    #pragma unroll
    for (int kk = 0; kk < 2; ++kk) {
      const int c16 = kk * 4 + (l >> 4);
      s16x8 af[4], bfr[4];
      #pragma unroll
      for (int mf = 0; mf < 4; ++mf) {
        const int r = wr + mf * 16 + (l & 15);
        af[mf] = *(const s16x8*)&As[cur][r * 64 + ((c16 ^ (r & 7)) << 3)];
      }
      #pragma unroll
      for (int nf = 0; nf < 4; ++nf) {
        const int r = wc + nf * 16 + (l & 15);
        bfr[nf] = *(const s16x8*)&Bs[cur][r * 64 + ((c16 ^ (r & 7)) << 3)];
      }
      __builtin_amdgcn_s_setprio(1);
      #pragma unroll
      for (int mf = 0; mf < 4; ++mf)
        #pragma unroll
        for (int nf = 0; nf < 4; ++nf)
          acc[mf][nf] = __builtin_amdgcn_mfma_f32_16x16x32_bf16(af[mf], bfr[nf], acc[mf][nf], 0, 0, 0);
      __builtin_amdgcn_s_setprio(0);
    }
    __syncthreads();   // drains the prefetch + publishes buf cur^1
  }
#undef STAGE_Q

  const int colB = n0 + wc;
  const int sec = colB >> 10;
  const int hh = (colB >> 6) & 15;
  if (sec < 2) {
    short* dst = sec ? kbO : qbO;
    const float* nw = sec ? knw : qnw;
    const float scl = sec ? 1.f : 0.125f;
    #pragma unroll
    for (int mf = 0; mf < 4; ++mf) {
      #pragma unroll
      for (int i = 0; i < 4; ++i) {
        const int row = m0 + wr + mf * 16 + ((l >> 4) << 2) + i;
        float vv[4];
        float ss = 0.f;
        #pragma unroll
        for (int nf = 0; nf < 4; ++nf) {
          vv[nf] = acc[mf][nf][i] + bias[colB + nf * 16 + (l & 15)];
          ss += vv[nf] * vv[nf];
        }
        ss += __shfl_xor(ss, 1); ss += __shfl_xor(ss, 2);
        ss += __shfl_xor(ss, 4); ss += __shfl_xor(ss, 8);
        const float rs = rsqrtf(ss * (1.f / 64.f) + 1e-6f) * scl;
        const int bb = row >> 10, nn = row & 1023;
        #pragma unroll
        for (int nf = 0; nf < 4; ++nf) {
          const int d = nf * 16 + (l & 15);
          dst[((size_t)(bb * 16 + hh) * 1024 + nn) * 64 + d] = f2bf(vv[nf] * rs * nw[d]);
        }
      }
    }
  } else {
    #pragma unroll
    for (int mf = 0; mf < 4; ++mf)
      #pragma unroll
      for (int nf = 0; nf < 4; ++nf) {
        const int col = colB + nf * 16 + (l & 15);
        const float bsv = bias[col];
        #pragma unroll
        for (int i = 0; i < 4; ++i) {
          const int row = m0 + wr + mf * 16 + ((l >> 4) << 2) + i;
          vrO[(size_t)row * 1024 + (col - 2048)] = f2bf(acc[mf][nf][i] + bsv);
        }
      }
  }
}

// ---------------- 128x64 GEMM (proj / w3): 2-phase dbuf, resid + ada gate ----------------
// MODE 1 (proj): resid fp32, out bf16.  MODE 4 (w3): resid bf16, out fp32.
template <int MODE>
__launch_bounds__(256, 2)
__global__ void gemm_pw(const short* __restrict__ A, const short* __restrict__ Bt,
                        const int K,
                        const float* __restrict__ bias,
                        const float* __restrict__ adav,
                        const float* __restrict__ residF,
                        const short* __restrict__ residB,
                        void* __restrict__ outP) {
  __shared__ short As[2][128 * 64];
  __shared__ short Bs[2][64 * 64];
  const int t = threadIdx.x;
  const int l = t & 63;
  const int w = t >> 6;
  const int wr = (w >> 1) * 64, wc = (w & 1) * 32;

  const int nwg = gridDim.x * gridDim.y;
  int lin = blockIdx.y * gridDim.x + blockIdx.x;
  lin = (lin & 7) * (nwg >> 3) + (lin >> 3);
  const int m0 = (lin / gridDim.x) * 128;
  const int n0 = (lin % gridDim.x) * 64;
  const int nT = K >> 6;

  f32x4 acc[4][2];
  const f32x4 z4 = {0.f, 0.f, 0.f, 0.f};
  #pragma unroll
  for (int i = 0; i < 4; ++i)
    #pragma unroll
    for (int j = 0; j < 2; ++j) acc[i][j] = z4;

  const int lr = l >> 3;
  const int lc = (l & 7) ^ lr;
  const short* gAs = A + (size_t)(m0 + w * 32 + lr) * K + lc * 8;
  const short* gBs = Bt + (size_t)(n0 + w * 16 + lr) * K + lc * 8;

#define STAGE_P(buf, kt)                                                       \
  do {                                                                         \
    const int _ko = (kt) * 64;                                                 \
    _Pragma("unroll") for (int p = 0; p < 4; ++p)                              \
      gload16(gAs + (size_t)p * 8 * K + _ko, &As[buf][(w * 32 + p * 8) * 64]); \
    _Pragma("unroll") for (int p = 0; p < 2; ++p)                              \
      gload16(gBs + (size_t)p * 8 * K + _ko, &Bs[buf][(w * 16 + p * 8) * 64]); \
  } while (0)

  STAGE_P(0, 0);
  __syncthreads();

  for (int kt = 0; kt < nT; ++kt) {
    const int cur = kt & 1;
    if (kt + 1 < nT) STAGE_P(cur ^ 1, kt + 1);
    #pragma unroll
    for (int kk = 0; kk < 2; ++kk) {
      const int c16 = kk * 4 + (l >> 4);
      s16x8 af[4], bfr[2];
      #pragma unroll
      for (int mf = 0; mf < 4; ++mf) {
        const int r = wr + mf * 16 + (l & 15);
        af[mf] = *(const s16x8*)&As[cur][r * 64 + ((c16 ^ (r & 7)) << 3)];
      }
      #pragma unroll
      for (int nf = 0; nf < 2; ++nf) {
        const int r = wc + nf * 16 + (l & 15);
        bfr[nf] = *(const s16x8*)&Bs[cur][r * 64 + ((c16 ^ (r & 7)) << 3)];
      }
      __builtin_amdgcn_s_setprio(1);
      #pragma unroll
      for (int mf = 0; mf < 4; ++mf)
        #pragma unroll
        for (int nf = 0; nf < 2; ++nf)
          acc[mf][nf] = __builtin_amdgcn_mfma_f32_16x16x32_bf16(af[mf], bfr[nf], acc[mf][nf], 0, 0, 0);
      __builtin_amdgcn_s_setprio(0);
    }
    __syncthreads();
  }
#undef STAGE_P

  const int bIdx = m0 >> 10;
  #pragma unroll
  for (int mf = 0; mf < 4; ++mf) {
    const int row = m0 + wr + mf * 16 + ((l >> 4) << 2);
    #pragma unroll
    for (int nf = 0; nf < 2; ++nf) {
      const int col = n0 + wc + nf * 16 + (l & 15);
      const float bsv = bias[col];
      const float av = adav[bIdx * 6144 + col];
      #pragma unroll
      for (int i = 0; i < 4; ++i) {
        const float v = acc[mf][nf][i] + bsv;
        const size_t idx = (size_t)(row + i) * 1024 + col;
        if (MODE == 1)
          ((short*)outP)[idx] = f2bf(residF[idx] + av * v);
        else
          ((float*)outP)[idx] = bf2f(residB[idx]) + av * v;
      }
    }
  }
}

// ---------------- w12 GEMM: 128x128-per-half tile, fused SwiGLU (round-14 frozen) ----------------
__launch_bounds__(256, 2)
__global__ void gemm_w12(const short* __restrict__ A, const short* __restrict__ Bt,
                         const float* __restrict__ bias, short* __restrict__ outH) {
  __shared__ short As[128 * 64];
  __shared__ short B1s[128 * 64];
  __shared__ short B2s[128 * 64];
  const int t = threadIdx.x;
  const int l = t & 63;
  const int w = t >> 6;
  const int wr = (w >> 1) * 64, wc = (w & 1) * 64;

  const int nwg = gridDim.x * gridDim.y;
  int lin = blockIdx.y * gridDim.x + blockIdx.x;
  lin = (lin & 7) * (nwg >> 3) + (lin >> 3);
  const int m0 = (lin / gridDim.x) * 128;
  const int n0 = (lin % gridDim.x) * 128;

  f32x4 a1[4][4], a2[4][4];
  const f32x4 z4 = {0.f, 0.f, 0.f, 0.f};
  #pragma unroll
  for (int i = 0; i < 4; ++i)
    #pragma unroll
    for (int j = 0; j < 4; ++j) { a1[i][j] = z4; a2[i][j] = z4; }

  const int lr = l >> 3;
  const int lc = (l & 7) ^ lr;
  const short* gAs = A + (size_t)(m0 + w * 32 + lr) * 1024 + lc * 8;
  const int rbase = n0 + w * 32 + lr;   // B row (clamped below)
  short* lA = As + (w * 32) * 64;
  short* lB1 = B1s + (w * 32) * 64;
  short* lB2 = B2s + (w * 32) * 64;

  for (int kt = 0; kt < 16; ++kt) {
    if (kt) __syncthreads();
    const int ko = kt * 64;
    #pragma unroll
    for (int p = 0; p < 4; ++p) {
      int j = rbase + p * 8;
      if (j >= FFH_) j = FFH_ - 1;       // clamp; epilogue masks
      gload16(gAs + (size_t)p * 8 * 1024 + ko, lA + p * 8 * 64);
      gload16(Bt + (size_t)j * 1024 + ko + lc * 8, lB1 + p * 8 * 64);
      gload16(Bt + (size_t)(j + FFH_) * 1024 + ko + lc * 8, lB2 + p * 8 * 64);
    }
    __syncthreads();
    #pragma unroll
    for (int kk = 0; kk < 2; ++kk) {
      const int c16 = kk * 4 + (l >> 4);
      s16x8 af[4], b1f[4], b2f[4];
      #pragma unroll
      for (int mf = 0; mf < 4; ++mf) {
        const int r = wr + mf * 16 + (l & 15);
        af[mf] = *(const s16x8*)&As[r * 64 + ((c16 ^ (r & 7)) << 3)];
      }
      #pragma unroll
      for (int nf = 0; nf < 4; ++nf) {
        const int r = wc + nf * 16 + (l & 15);
        const int idx = r * 64 + ((c16 ^ (r & 7)) << 3);
        b1f[nf] = *(const s16x8*)&B1s[idx];
        b2f[nf] = *(const s16x8*)&B2s[idx];
      }
      __builtin_amdgcn_s_setprio(1);
      #pragma unroll
      for (int mf = 0; mf < 4; ++mf)
        #pragma unroll
        for (int nf = 0; nf < 4; ++nf) {
          a1[mf][nf] = __builtin_amdgcn_mfma_f32_16x16x32_bf16(af[mf], b1f[nf], a1[mf][nf], 0, 0, 0);
          a2[mf][nf] = __builtin_amdgcn_mfma_f32_16x16x32_bf16(af[mf], b2f[nf], a2[mf][nf], 0, 0, 0);
        }
      __builtin_amdgcn_s_setprio(0);
    }
  }

  #pragma unroll
  for (int mf = 0; mf < 4; ++mf) {
    const int row = m0 + wr + mf * 16 + ((l >> 4) << 2);
    #pragma unroll
    for (int nf = 0; nf < 4; ++nf) {
      const int col = n0 + wc + nf * 16 + (l & 15);
      if (col < FFP_) {
        const bool real = col < FFH_;
        const float bb1 = real ? bias[col] : 0.f;
        const float bb2 = real ? bias[col + FFH_] : 0.f;
        #pragma unroll
        for (int i = 0; i < 4; ++i) {
          float o = 0.f;
          if (real) {
            const float v1 = a1[mf][nf][i] + bb1;
            const float v2 = a2[mf][nf][i] + bb2;
            o = silu(v1) * v2;
          }
          outH[(size_t)(row + i) * FFP_ + col] = f2bf(o);
        }
      }
    }
  }
}

// ---------------- V transpose bf16 (B,N,C)->(B,H,D,N) ----------------
__global__ void v_trans(const short* __restrict__ vr, short* __restrict__ vt) {
  __shared__ short ld[64][72];
  const int t = threadIdx.x;
  const int bh = blockIdx.y, b = bh >> 4, h = bh & 15;
  const int n0 = blockIdx.x * 64;
  const int nl = t >> 2, cb = (t & 3) * 16;
  const short* src = vr + (size_t)(b * 1024 + n0 + nl) * 1024 + h * 64 + cb;
  *(s16x8*)&ld[nl][cb] = *(const s16x8*)src;
  *(s16x8*)&ld[nl][cb + 8] = *(const s16x8*)(src + 8);
  __syncthreads();
  const int d = t >> 2, np = (t & 3) * 16;
  short* dst = vt + (size_t)(bh * 64 + d) * 1024 + n0 + np;
  s16x8 o0, o1;
  #pragma unroll
  for (int p = 0; p < 8; ++p) { o0[p] = ld[np + p][d]; o1[p] = ld[np + 8 + p][d]; }
  *(s16x8*)dst = o0;
  *(s16x8*)(dst + 8) = o1;
}

// ---------------- flash attention (XCD-local KV + defer-max) ----------------
__launch_bounds__(256, 2)
__global__ void attn(const short* __restrict__ qb, const short* __restrict__ kb,
                     const short* __restrict__ vt, short* __restrict__ ob) {
  __shared__ short Ks[64 * 64];
  __shared__ short Vs[64 * 64];
  __shared__ short Pl[4][32 * 64];
  const int t = threadIdx.x, l = t & 63, w = t >> 6;
  const int lin = blockIdx.y * gridDim.x + blockIdx.x;
  const int xcd = lin & 7, slot = lin >> 3;
  const int bh = xcd * 8 + (slot >> 3);
  const int b = bh >> 4, h = bh & 15;
  const int q0 = (slot & 7) * 128 + w * 32;
  const short* qp = qb + (size_t)bh * (N_ * D_);
  const short* kp = kb + (size_t)bh * (N_ * D_);
  const short* vp = vt + (size_t)bh * (D_ * N_);

  s16x8 qf[2][2];
  #pragma unroll
  for (int mf = 0; mf < 2; ++mf)
    #pragma unroll
    for (int kk = 0; kk < 2; ++kk)
      qf[mf][kk] = *(const s16x8*)&qp[(q0 + mf * 16 + (l & 15)) * 64 + kk * 32 + ((l >> 4) * 8)];

  f32x4 aco[2][4];
  float rm[2][4], rl[2][4];
  const f32x4 z4 = {0.f, 0.f, 0.f, 0.f};
  #pragma unroll
  for (int mf = 0; mf < 2; ++mf) {
    #pragma unroll
    for (int nd = 0; nd < 4; ++nd) aco[mf][nd] = z4;
    #pragma unroll
    for (int i = 0; i < 4; ++i) { rm[mf][i] = -1e30f; rl[mf][i] = 0.f; }
  }

  const int sr = t >> 2, sc = (t & 3) * 2;
  s16x8 rk[2], rv[2];
  #pragma unroll
  for (int p = 0; p < 2; ++p) {
    rk[p] = *(const s16x8*)&kp[sr * 64 + (sc + p) * 8];
    rv[p] = *(const s16x8*)&vp[sr * 1024 + (sc + p) * 8];
  }

  for (int kt = 0; kt < 16; ++kt) {
    if (kt) __syncthreads();
    #pragma unroll
    for (int p = 0; p < 2; ++p) {
      const int cs = ((sc + p) ^ (sr & 7)) << 3;
      *(s16x8*)&Ks[sr * 64 + cs] = rk[p];
      *(s16x8*)&Vs[sr * 64 + cs] = rv[p];
    }
    __syncthreads();
    if (kt < 15) {
      const int kv0 = (kt + 1) * 64;
      #pragma unroll
      for (int p = 0; p < 2; ++p) {
        rk[p] = *(const s16x8*)&kp[(kv0 + sr) * 64 + (sc + p) * 8];
        rv[p] = *(const s16x8*)&vp[sr * 1024 + kv0 + (sc + p) * 8];
      }
    }

    f32x4 s[2][4];
    #pragma unroll
    for (int mf = 0; mf < 2; ++mf)
      #pragma unroll
      for (int nf = 0; nf < 4; ++nf) s[mf][nf] = z4;

    #pragma unroll
    for (int kk = 0; kk < 2; ++kk) {
      const int c16 = kk * 4 + (l >> 4);
      s16x8 kf[4];
      #pragma unroll
      for (int nf = 0; nf < 4; ++nf) {
        const int r = nf * 16 + (l & 15);
        kf[nf] = *(const s16x8*)&Ks[r * 64 + ((c16 ^ (r & 7)) << 3)];
      }
      __builtin_amdgcn_s_setprio(1);
      #pragma unroll
      for (int mf = 0; mf < 2; ++mf)
        #pragma unroll
        for (int nf = 0; nf < 4; ++nf)
          s[mf][nf] = __builtin_amdgcn_mfma_f32_16x16x32_bf16(qf[mf][kk], kf[nf], s[mf][nf], 0, 0, 0);
      __builtin_amdgcn_s_setprio(0);
    }

    #pragma unroll
    for (int mf = 0; mf < 2; ++mf) {
      #pragma unroll
      for (int i = 0; i < 4; ++i) {
        float pm = fmaxf(fmaxf(s[mf][0][i], s[mf][1][i]), fmaxf(s[mf][2][i], s[mf][3][i]));
        pm = fmaxf(pm, __shfl_xor(pm, 1));
        pm = fmaxf(pm, __shfl_xor(pm, 2));
        pm = fmaxf(pm, __shfl_xor(pm, 4));
        pm = fmaxf(pm, __shfl_xor(pm, 8));
        if (!__all(pm - rm[mf][i] <= 8.f)) {
          const float nm = fmaxf(rm[mf][i], pm);
          const float corr = __expf(rm[mf][i] - nm);
          rm[mf][i] = nm;
          rl[mf][i] *= corr;
          #pragma unroll
          for (int nd = 0; nd < 4; ++nd) aco[mf][nd][i] *= corr;
        }
        float rs = 0.f;
        #pragma unroll
        for (int nf = 0; nf < 4; ++nf) {
          const float p = __expf(s[mf][nf][i] - rm[mf][i]);
          s[mf][nf][i] = p;
          rs += p;
        }
        rs += __shfl_xor(rs, 1);
        rs += __shfl_xor(rs, 2);
        rs += __shfl_xor(rs, 4);
        rs += __shfl_xor(rs, 8);
        rl[mf][i] += rs;
      }
    }

    short* pw = &Pl[w][0];
    #pragma unroll
    for (int mf = 0; mf < 2; ++mf)
      #pragma unroll
      for (int nf = 0; nf < 4; ++nf)
        #pragma unroll
        for (int i = 0; i < 4; ++i) {
          const int row = mf * 16 + ((l >> 4) << 2) + i;
          const int col = nf * 16 + (l & 15);
          pw[row * 64 + (((col >> 3) ^ (row & 7)) << 3) + (col & 7)] = f2bf(s[mf][nf][i]);
        }

    #pragma unroll
    for (int kk = 0; kk < 2; ++kk) {
      const int c16 = kk * 4 + (l >> 4);
      s16x8 vf[4];
      #pragma unroll
      for (int nd = 0; nd < 4; ++nd) {
        const int r = nd * 16 + (l & 15);
        vf[nd] = *(const s16x8*)&Vs[r * 64 + ((c16 ^ (r & 7)) << 3)];
      }
      __builtin_amdgcn_s_setprio(1);
      #pragma unroll
      for (int mf = 0; mf < 2; ++mf) {
        const int pr = mf * 16 + (l & 15);
        const s16x8 pf = *(const s16x8*)&pw[pr * 64 + ((c16 ^ (pr & 7)) << 3)];
        #pragma unroll
        for (int nd = 0; nd < 4; ++nd)
          aco[mf][nd] = __builtin_amdgcn_mfma_f32_16x16x32_bf16(pf, vf[nd], aco[mf][nd], 0, 0, 0);
      }
      __builtin_amdgcn_s_setprio(0);
    }
  }

  #pragma unroll
  for (int mf = 0; mf < 2; ++mf)
    #pragma unroll
    for (int i = 0; i < 4; ++i) {
      const float inv = 1.f / rl[mf][i];
      const int row = q0 + mf * 16 + ((l >> 4) << 2) + i;
      #pragma unroll
      for (int nd = 0; nd < 4; ++nd) {
        const int col = h * 64 + nd * 16 + (l & 15);
        ob[(size_t)(b * 1024 + row) * 1024 + col] = f2bf(aco[mf][nd][i] * inv);
      }
    }
}

// ---------------- host launcher ----------------
extern "C" void kernel_launch(void* const* d_in, const int* in_sizes, int n_in,
                              void* d_out, int out_size, void* d_ws, size_t ws_size,
                              hipStream_t stream) {
  const float* x     = (const float*)d_in[0];
  const float* c     = (const float*)d_in[1];
  const float* n1w   = (const float*)d_in[2];
  const float* n2w   = (const float*)d_in[3];
  const float* qkvw  = (const float*)d_in[4];
  const float* qkvb  = (const float*)d_in[5];
  const float* qnw   = (const float*)d_in[6];
  const float* knw   = (const float*)d_in[7];
  const float* projw = (const float*)d_in[8];
  const float* projb = (const float*)d_in[9];
  const float* w12w  = (const float*)d_in[10];
  const float* w12b  = (const float*)d_in[11];
  const float* w3w   = (const float*)d_in[12];
  const float* w3b   = (const float*)d_in[13];
  const float* adaw  = (const float*)d_in[14];
  const float* adab  = (const float*)d_in[15];
  float* outp = (float*)d_out;

  char* ws = (char*)d_ws;
  size_t off = 0;
  auto alloc = [&](size_t bytes) { void* p = ws + off; off += (bytes + 255) & ~(size_t)255; return p; };
  short* WQKV = (short*)alloc(3072ull * 1024 * 2);
  short* WPROJ = (short*)alloc(1024ull * 1024 * 2);
  short* W12B = (short*)alloc(5460ull * 1024 * 2);
  short* W3B  = (short*)alloc(1024ull * FFP_ * 2);
  float* ADA  = (float*)alloc(4ull * 6144 * 4);
  short* H1   = (short*)alloc(4096ull * 1024 * 2);
  short* QBF  = (short*)alloc(64ull * 1024 * 64 * 2);
  short* KBF  = (short*)alloc(64ull * 1024 * 64 * 2);
  short* VROW = (short*)alloc(4096ull * 1024 * 2);
  short* VTB  = (short*)alloc(64ull * 64 * 1024 * 2);
  short* OBF  = (short*)alloc(4096ull * 1024 * 2);
  short* X1B  = (short*)alloc(4096ull * 1024 * 2);
  short* H2   = (short*)alloc(4096ull * 1024 * 2);
  short* HB   = (short*)alloc(4096ull * FFP_ * 2);

  cvt4<<<2048, 256, 0, stream>>>(qkvw, WQKV, 3072 * 1024 / 4,
                                 projw, WPROJ, 1024 * 1024 / 4,
                                 w12w, W12B, 5460 * 1024 / 4,
                                 w3w, W3B, 1024 * (FFP_ / 4));
  ada_gemm<<<6144, 64, 0, stream>>>(c, adaw, adab, ADA);
  rmsmod<<<4096, 256, 0, stream>>>(x, n1w, ADA, 0, 1024, H1);
  gemm_qkv<<<dim3(24, 32), 256, 0, stream>>>(H1, WQKV, qkvb, QBF, KBF, VROW, qnw, knw);
  v_trans<<<dim3(16, 64), 256, 0, stream>>>(VROW, VTB);
  attn<<<dim3(8, 64), 256, 0, stream>>>(QBF, KBF, VTB, OBF);
  gemm_pw<1><<<dim3(16, 32), 256, 0, stream>>>(OBF, WPROJ, 1024, projb,
      ADA + 2048, x, nullptr, X1B);
  rmsmod_b<<<4096, 256, 0, stream>>>(X1B, n2w, ADA, 3072, 4096, H2);
  gemm_w12<<<dim3(22, 32), 256, 0, stream>>>(H2, W12B, w12b, HB);
  gemm_pw<4><<<dim3(16, 32), 256, 0, stream>>>(HB, W3B, FFP_, w3b,
      ADA + 5120, nullptr, X1B, outp);
}

// Round 20
// 256.183 us; speedup vs baseline: 1.0023x; 1.0023x over previous
//
#include <hip/hip_runtime.h>

typedef short s16x8 __attribute__((ext_vector_type(8)));
typedef short s16x4 __attribute__((ext_vector_type(4)));
typedef float f32x4 __attribute__((ext_vector_type(4)));

#define B_   4
#define N_   1024
#define C_   1024
#define H_   16
#define D_   64
#define FFH_ 2730
#define FFP_ 2752

__device__ __forceinline__ short f2bf(float f) {
  unsigned u = __float_as_uint(f);
  u += 0x7fff + ((u >> 16) & 1);           // RNE to bf16
  return (short)(unsigned short)(u >> 16);
}
__device__ __forceinline__ float bf2f(short s) {
  return __uint_as_float(((unsigned)(unsigned short)s) << 16);
}
__device__ __forceinline__ float silu(float x) { return x / (1.f + __expf(-x)); }

// async global->LDS, 16B per lane; LDS dest is wave-uniform base + lane*16
__device__ __forceinline__ void gload16(const void* g, void* l) {
  __builtin_amdgcn_global_load_lds(
      (const __attribute__((address_space(1))) unsigned*)g,
      (__attribute__((address_space(3))) unsigned*)l, 16, 0, 0);
}

// ---------------- weight conversion: qkv + proj + w12 + padded w3, one launch ----------------
__global__ void cvt4(const float* __restrict__ s0, short* __restrict__ d0, const int n0,
                     const float* __restrict__ s1, short* __restrict__ d1, const int n1,
                     const float* __restrict__ s2, short* __restrict__ d2, const int n2,
                     const float* __restrict__ s3, short* __restrict__ d3, const int n3) {
  const int tot = n0 + n1 + n2 + n3;
  for (int i = blockIdx.x * 256 + threadIdx.x; i < tot; i += gridDim.x * 256) {
    int j = i;
    if (j < n0) {
      const float4 v = ((const float4*)s0)[j];
      s16x4 o; o[0] = f2bf(v.x); o[1] = f2bf(v.y); o[2] = f2bf(v.z); o[3] = f2bf(v.w);
      *(s16x4*)(d0 + (size_t)j * 4) = o;
    } else if ((j -= n0) < n1) {
      const float4 v = ((const float4*)s1)[j];
      s16x4 o; o[0] = f2bf(v.x); o[1] = f2bf(v.y); o[2] = f2bf(v.z); o[3] = f2bf(v.w);
      *(s16x4*)(d1 + (size_t)j * 4) = o;
    } else if ((j -= n1) < n2) {
      const float4 v = ((const float4*)s2)[j];
      s16x4 o; o[0] = f2bf(v.x); o[1] = f2bf(v.y); o[2] = f2bf(v.z); o[3] = f2bf(v.w);
      *(s16x4*)(d2 + (size_t)j * 4) = o;
    } else {
      j -= n2;
      const int row = j / (FFP_ / 4);
      const int cb = (j % (FFP_ / 4)) * 4;
      s16x4 o;
      #pragma unroll
      for (int e = 0; e < 4; ++e) {
        const int col = cb + e;
        o[e] = (col < FFH_) ? f2bf(s3[(size_t)row * FFH_ + col]) : (short)0;
      }
      *(s16x4*)(d3 + (size_t)row * FFP_ + cb) = o;
    }
  }
}

// ---------------- ada = silu(c) @ ada_w.T + ada_b ----------------
__global__ void ada_gemm(const float* __restrict__ c, const float* __restrict__ aw,
                         const float* __restrict__ ab, float* __restrict__ ada) {
  const int j = blockIdx.x;
  const int l = threadIdx.x;
  float acc[4] = {0.f, 0.f, 0.f, 0.f};
  const float4* wr = (const float4*)(aw + (size_t)j * 1024);
  #pragma unroll
  for (int p = 0; p < 4; ++p) {
    const float4 wv = wr[p * 64 + l];
    #pragma unroll
    for (int b = 0; b < 4; ++b) {
      const float4 cv = ((const float4*)(c + b * 1024))[p * 64 + l];
      acc[b] += silu(cv.x) * wv.x + silu(cv.y) * wv.y + silu(cv.z) * wv.z + silu(cv.w) * wv.w;
    }
  }
  #pragma unroll
  for (int b = 0; b < 4; ++b) {
    float a = acc[b];
    #pragma unroll
    for (int m = 1; m < 64; m <<= 1) a += __shfl_xor(a, m);
    if (l == 0) ada[b * 6144 + j] = a + ab[j];
  }
}

// ---------------- fused rmsnorm + modulate (fp32 in) -> bf16 ----------------
__global__ void rmsmod(const float* __restrict__ x, const float* __restrict__ wn,
                       const float* __restrict__ ada, const int sOff, const int gOff,
                       short* __restrict__ out) {
  const int row = blockIdx.x;
  const int b = row >> 10;
  const int t = threadIdx.x;
  const float4 v = ((const float4*)(x + (size_t)row * 1024))[t];
  float ss = v.x * v.x + v.y * v.y + v.z * v.z + v.w * v.w;
  #pragma unroll
  for (int m = 1; m < 64; m <<= 1) ss += __shfl_xor(ss, m);
  __shared__ float red[4];
  if ((t & 63) == 0) red[t >> 6] = ss;
  __syncthreads();
  const float rs = rsqrtf((red[0] + red[1] + red[2] + red[3]) * (1.f / 1024.f) + 1e-6f);
  const int j = t * 4;
  const float* sp = ada + b * 6144 + sOff + j;
  const float* gp = ada + b * 6144 + gOff + j;
  s16x4 o;
  o[0] = f2bf(v.x * rs * wn[j + 0] * (1.f + gp[0]) + sp[0]);
  o[1] = f2bf(v.y * rs * wn[j + 1] * (1.f + gp[1]) + sp[1]);
  o[2] = f2bf(v.z * rs * wn[j + 2] * (1.f + gp[2]) + sp[2]);
  o[3] = f2bf(v.w * rs * wn[j + 3] * (1.f + gp[3]) + sp[3]);
  *(s16x4*)(out + (size_t)row * 1024 + j) = o;
}

// ---------------- fused rmsnorm + modulate (bf16 in) -> bf16 ----------------
__global__ void rmsmod_b(const short* __restrict__ x, const float* __restrict__ wn,
                         const float* __restrict__ ada, const int sOff, const int gOff,
                         short* __restrict__ out) {
  const int row = blockIdx.x;
  const int b = row >> 10;
  const int t = threadIdx.x;
  const s16x4 vb = *(const s16x4*)(x + (size_t)row * 1024 + t * 4);
  const float v0 = bf2f(vb[0]), v1 = bf2f(vb[1]), v2 = bf2f(vb[2]), v3 = bf2f(vb[3]);
  float ss = v0 * v0 + v1 * v1 + v2 * v2 + v3 * v3;
  #pragma unroll
  for (int m = 1; m < 64; m <<= 1) ss += __shfl_xor(ss, m);
  __shared__ float red[4];
  if ((t & 63) == 0) red[t >> 6] = ss;
  __syncthreads();
  const float rs = rsqrtf((red[0] + red[1] + red[2] + red[3]) * (1.f / 1024.f) + 1e-6f);
  const int j = t * 4;
  const float* sp = ada + b * 6144 + sOff + j;
  const float* gp = ada + b * 6144 + gOff + j;
  s16x4 o;
  o[0] = f2bf(v0 * rs * wn[j + 0] * (1.f + gp[0]) + sp[0]);
  o[1] = f2bf(v1 * rs * wn[j + 1] * (1.f + gp[1]) + sp[1]);
  o[2] = f2bf(v2 * rs * wn[j + 2] * (1.f + gp[2]) + sp[2]);
  o[3] = f2bf(v3 * rs * wn[j + 3] * (1.f + gp[3]) + sp[3]);
  *(s16x4*)(out + (size_t)row * 1024 + j) = o;
}

// ---------------- qkv GEMM: 128x128 tile, 2-phase dbuf, fused q/k rmsnorm + v ----------------
__launch_bounds__(256, 2)
__global__ void gemm_qkv(const short* __restrict__ A, const short* __restrict__ Bt,
                         const float* __restrict__ bias,
                         short* __restrict__ qbO, short* __restrict__ kbO,
                         short* __restrict__ vrO,
                         const float* __restrict__ qnw, const float* __restrict__ knw) {
  __shared__ short As[2][128 * 64];
  __shared__ short Bs[2][128 * 64];
  const int t = threadIdx.x;
  const int l = t & 63;
  const int w = t >> 6;
  const int wr = (w >> 1) * 64, wc = (w & 1) * 64;
  const int K = 1024;

  const int nwg = gridDim.x * gridDim.y;
  int lin = blockIdx.y * gridDim.x + blockIdx.x;
  lin = (lin & 7) * (nwg >> 3) + (lin >> 3);
  const int m0 = (lin / gridDim.x) * 128;
  const int n0 = (lin % gridDim.x) * 128;

  f32x4 acc[4][4];
  const f32x4 z4 = {0.f, 0.f, 0.f, 0.f};
  #pragma unroll
  for (int i = 0; i < 4; ++i)
    #pragma unroll
    for (int j = 0; j < 4; ++j) acc[i][j] = z4;

  const int lr = l >> 3;
  const int lc = (l & 7) ^ lr;          // pre-swizzled source chunk (rule #21)
  const short* gAs = A + (size_t)(m0 + w * 32 + lr) * K + lc * 8;
  const short* gBs = Bt + (size_t)(n0 + w * 32 + lr) * K + lc * 8;
  const int wofs = (w * 32) * 64;

#define STAGE_Q(buf, kt)                                                       \
  do {                                                                         \
    const int _ko = (kt) * 64;                                                 \
    _Pragma("unroll") for (int p = 0; p < 4; ++p) {                            \
      gload16(gAs + (size_t)p * 8 * K + _ko, &As[buf][wofs + p * 8 * 64]);     \
      gload16(gBs + (size_t)p * 8 * K + _ko, &Bs[buf][wofs + p * 8 * 64]);     \
    }                                                                          \
  } while (0)

  STAGE_Q(0, 0);
  __syncthreads();

  for (int kt = 0; kt < 16; ++kt) {
    const int cur = kt & 1;
    if (kt + 1 < 16) STAGE_Q(cur ^ 1, kt + 1);   // loads in flight during MFMA
    #pragma unroll
    for (int kk = 0; kk < 2; ++kk) {
      const int c16 = kk * 4 + (l >> 4);
      s16x8 af[4], bfr[4];
      #pragma unroll
      for (int mf = 0; mf < 4; ++mf) {
        const int r = wr + mf * 16 + (l & 15);
        af[mf] = *(const s16x8*)&As[cur][r * 64 + ((c16 ^ (r & 7)) << 3)];
      }
      #pragma unroll
      for (int nf = 0; nf < 4; ++nf) {
        const int r = wc + nf * 16 + (l & 15);
        bfr[nf] = *(const s16x8*)&Bs[cur][r * 64 + ((c16 ^ (r & 7)) << 3)];
      }
      __builtin_amdgcn_s_setprio(1);
      #pragma unroll
      for (int mf = 0; mf < 4; ++mf)
        #pragma unroll
        for (int nf = 0; nf < 4; ++nf)
          acc[mf][nf] = __builtin_amdgcn_mfma_f32_16x16x32_bf16(af[mf], bfr[nf], acc[mf][nf], 0, 0, 0);
      __builtin_amdgcn_s_setprio(0);
    }
    __syncthreads();   // drains the prefetch + publishes buf cur^1
  }
#undef STAGE_Q

  const int colB = n0 + wc;
  const int sec = colB >> 10;
  const int hh = (colB >> 6) & 15;
  if (sec < 2) {
    short* dst = sec ? kbO : qbO;
    const float* nw = sec ? knw : qnw;
    const float scl = sec ? 1.f : 0.125f;
    #pragma unroll
    for (int mf = 0; mf < 4; ++mf) {
      #pragma unroll
      for (int i = 0; i < 4; ++i) {
        const int row = m0 + wr + mf * 16 + ((l >> 4) << 2) + i;
        float vv[4];
        float ss = 0.f;
        #pragma unroll
        for (int nf = 0; nf < 4; ++nf) {
          vv[nf] = acc[mf][nf][i] + bias[colB + nf * 16 + (l & 15)];
          ss += vv[nf] * vv[nf];
        }
        ss += __shfl_xor(ss, 1); ss += __shfl_xor(ss, 2);
        ss += __shfl_xor(ss, 4); ss += __shfl_xor(ss, 8);
        const float rs = rsqrtf(ss * (1.f / 64.f) + 1e-6f) * scl;
        const int bb = row >> 10, nn = row & 1023;
        #pragma unroll
        for (int nf = 0; nf < 4; ++nf) {
          const int d = nf * 16 + (l & 15);
          dst[((size_t)(bb * 16 + hh) * 1024 + nn) * 64 + d] = f2bf(vv[nf] * rs * nw[d]);
        }
      }
    }
  } else {
    #pragma unroll
    for (int mf = 0; mf < 4; ++mf)
      #pragma unroll
      for (int nf = 0; nf < 4; ++nf) {
        const int col = colB + nf * 16 + (l & 15);
        const float bsv = bias[col];
        #pragma unroll
        for (int i = 0; i < 4; ++i) {
          const int row = m0 + wr + mf * 16 + ((l >> 4) << 2) + i;
          vrO[(size_t)row * 1024 + (col - 2048)] = f2bf(acc[mf][nf][i] + bsv);
        }
      }
  }
}

// ---------------- 128x64 GEMM (proj / w3): 2-phase dbuf, resid + ada gate ----------------
// MODE 1 (proj): resid fp32, out bf16.  MODE 4 (w3): resid bf16, out fp32.
template <int MODE>
__launch_bounds__(256, 2)
__global__ void gemm_pw(const short* __restrict__ A, const short* __restrict__ Bt,
                        const int K,
                        const float* __restrict__ bias,
                        const float* __restrict__ adav,
                        const float* __restrict__ residF,
                        const short* __restrict__ residB,
                        void* __restrict__ outP) {
  __shared__ short As[2][128 * 64];
  __shared__ short Bs[2][64 * 64];
  const int t = threadIdx.x;
  const int l = t & 63;
  const int w = t >> 6;
  const int wr = (w >> 1) * 64, wc = (w & 1) * 32;

  const int nwg = gridDim.x * gridDim.y;
  int lin = blockIdx.y * gridDim.x + blockIdx.x;
  lin = (lin & 7) * (nwg >> 3) + (lin >> 3);
  const int m0 = (lin / gridDim.x) * 128;
  const int n0 = (lin % gridDim.x) * 64;
  const int nT = K >> 6;

  f32x4 acc[4][2];
  const f32x4 z4 = {0.f, 0.f, 0.f, 0.f};
  #pragma unroll
  for (int i = 0; i < 4; ++i)
    #pragma unroll
    for (int j = 0; j < 2; ++j) acc[i][j] = z4;

  const int lr = l >> 3;
  const int lc = (l & 7) ^ lr;
  const short* gAs = A + (size_t)(m0 + w * 32 + lr) * K + lc * 8;
  const short* gBs = Bt + (size_t)(n0 + w * 16 + lr) * K + lc * 8;

#define STAGE_P(buf, kt)                                                       \
  do {                                                                         \
    const int _ko = (kt) * 64;                                                 \
    _Pragma("unroll") for (int p = 0; p < 4; ++p)                              \
      gload16(gAs + (size_t)p * 8 * K + _ko, &As[buf][(w * 32 + p * 8) * 64]); \
    _Pragma("unroll") for (int p = 0; p < 2; ++p)                              \
      gload16(gBs + (size_t)p * 8 * K + _ko, &Bs[buf][(w * 16 + p * 8) * 64]); \
  } while (0)

  STAGE_P(0, 0);
  __syncthreads();

  for (int kt = 0; kt < nT; ++kt) {
    const int cur = kt & 1;
    if (kt + 1 < nT) STAGE_P(cur ^ 1, kt + 1);
    #pragma unroll
    for (int kk = 0; kk < 2; ++kk) {
      const int c16 = kk * 4 + (l >> 4);
      s16x8 af[4], bfr[2];
      #pragma unroll
      for (int mf = 0; mf < 4; ++mf) {
        const int r = wr + mf * 16 + (l & 15);
        af[mf] = *(const s16x8*)&As[cur][r * 64 + ((c16 ^ (r & 7)) << 3)];
      }
      #pragma unroll
      for (int nf = 0; nf < 2; ++nf) {
        const int r = wc + nf * 16 + (l & 15);
        bfr[nf] = *(const s16x8*)&Bs[cur][r * 64 + ((c16 ^ (r & 7)) << 3)];
      }
      __builtin_amdgcn_s_setprio(1);
      #pragma unroll
      for (int mf = 0; mf < 4; ++mf)
        #pragma unroll
        for (int nf = 0; nf < 2; ++nf)
          acc[mf][nf] = __builtin_amdgcn_mfma_f32_16x16x32_bf16(af[mf], bfr[nf], acc[mf][nf], 0, 0, 0);
      __builtin_amdgcn_s_setprio(0);
    }
    __syncthreads();
  }
#undef STAGE_P

  const int bIdx = m0 >> 10;
  #pragma unroll
  for (int mf = 0; mf < 4; ++mf) {
    const int row = m0 + wr + mf * 16 + ((l >> 4) << 2);
    #pragma unroll
    for (int nf = 0; nf < 2; ++nf) {
      const int col = n0 + wc + nf * 16 + (l & 15);
      const float bsv = bias[col];
      const float av = adav[bIdx * 6144 + col];
      #pragma unroll
      for (int i = 0; i < 4; ++i) {
        const float v = acc[mf][nf][i] + bsv;
        const size_t idx = (size_t)(row + i) * 1024 + col;
        if (MODE == 1)
          ((short*)outP)[idx] = f2bf(residF[idx] + av * v);
        else
          ((float*)outP)[idx] = bf2f(residB[idx]) + av * v;
      }
    }
  }
}

// ---------------- w12 GEMM: 128x128-per-half tile, fused SwiGLU (round-14 frozen) ----------------
__launch_bounds__(256, 2)
__global__ void gemm_w12(const short* __restrict__ A, const short* __restrict__ Bt,
                         const float* __restrict__ bias, short* __restrict__ outH) {
  __shared__ short As[128 * 64];
  __shared__ short B1s[128 * 64];
  __shared__ short B2s[128 * 64];
  const int t = threadIdx.x;
  const int l = t & 63;
  const int w = t >> 6;
  const int wr = (w >> 1) * 64, wc = (w & 1) * 64;

  const int nwg = gridDim.x * gridDim.y;
  int lin = blockIdx.y * gridDim.x + blockIdx.x;
  lin = (lin & 7) * (nwg >> 3) + (lin >> 3);
  const int m0 = (lin / gridDim.x) * 128;
  const int n0 = (lin % gridDim.x) * 128;

  f32x4 a1[4][4], a2[4][4];
  const f32x4 z4 = {0.f, 0.f, 0.f, 0.f};
  #pragma unroll
  for (int i = 0; i < 4; ++i)
    #pragma unroll
    for (int j = 0; j < 4; ++j) { a1[i][j] = z4; a2[i][j] = z4; }

  const int lr = l >> 3;
  const int lc = (l & 7) ^ lr;
  const short* gAs = A + (size_t)(m0 + w * 32 + lr) * 1024 + lc * 8;
  const int rbase = n0 + w * 32 + lr;   // B row (clamped below)
  short* lA = As + (w * 32) * 64;
  short* lB1 = B1s + (w * 32) * 64;
  short* lB2 = B2s + (w * 32) * 64;

  for (int kt = 0; kt < 16; ++kt) {
    if (kt) __syncthreads();
    const int ko = kt * 64;
    #pragma unroll
    for (int p = 0; p < 4; ++p) {
      int j = rbase + p * 8;
      if (j >= FFH_) j = FFH_ - 1;       // clamp; epilogue masks
      gload16(gAs + (size_t)p * 8 * 1024 + ko, lA + p * 8 * 64);
      gload16(Bt + (size_t)j * 1024 + ko + lc * 8, lB1 + p * 8 * 64);
      gload16(Bt + (size_t)(j + FFH_) * 1024 + ko + lc * 8, lB2 + p * 8 * 64);
    }
    __syncthreads();
    #pragma unroll
    for (int kk = 0; kk < 2; ++kk) {
      const int c16 = kk * 4 + (l >> 4);
      s16x8 af[4], b1f[4], b2f[4];
      #pragma unroll
      for (int mf = 0; mf < 4; ++mf) {
        const int r = wr + mf * 16 + (l & 15);
        af[mf] = *(const s16x8*)&As[r * 64 + ((c16 ^ (r & 7)) << 3)];
      }
      #pragma unroll
      for (int nf = 0; nf < 4; ++nf) {
        const int r = wc + nf * 16 + (l & 15);
        const int idx = r * 64 + ((c16 ^ (r & 7)) << 3);
        b1f[nf] = *(const s16x8*)&B1s[idx];
        b2f[nf] = *(const s16x8*)&B2s[idx];
      }
      __builtin_amdgcn_s_setprio(1);
      #pragma unroll
      for (int mf = 0; mf < 4; ++mf)
        #pragma unroll
        for (int nf = 0; nf < 4; ++nf) {
          a1[mf][nf] = __builtin_amdgcn_mfma_f32_16x16x32_bf16(af[mf], b1f[nf], a1[mf][nf], 0, 0, 0);
          a2[mf][nf] = __builtin_amdgcn_mfma_f32_16x16x32_bf16(af[mf], b2f[nf], a2[mf][nf], 0, 0, 0);
        }
      __builtin_amdgcn_s_setprio(0);
    }
  }

  #pragma unroll
  for (int mf = 0; mf < 4; ++mf) {
    const int row = m0 + wr + mf * 16 + ((l >> 4) << 2);
    #pragma unroll
    for (int nf = 0; nf < 4; ++nf) {
      const int col = n0 + wc + nf * 16 + (l & 15);
      if (col < FFP_) {
        const bool real = col < FFH_;
        const float bb1 = real ? bias[col] : 0.f;
        const float bb2 = real ? bias[col + FFH_] : 0.f;
        #pragma unroll
        for (int i = 0; i < 4; ++i) {
          float o = 0.f;
          if (real) {
            const float v1 = a1[mf][nf][i] + bb1;
            const float v2 = a2[mf][nf][i] + bb2;
            o = silu(v1) * v2;
          }
          outH[(size_t)(row + i) * FFP_ + col] = f2bf(o);
        }
      }
    }
  }
}

// ---------------- V transpose bf16 (B,N,C)->(B,H,D,N) ----------------
__global__ void v_trans(const short* __restrict__ vr, short* __restrict__ vt) {
  __shared__ short ld[64][72];
  const int t = threadIdx.x;
  const int bh = blockIdx.y, b = bh >> 4, h = bh & 15;
  const int n0 = blockIdx.x * 64;
  const int nl = t >> 2, cb = (t & 3) * 16;
  const short* src = vr + (size_t)(b * 1024 + n0 + nl) * 1024 + h * 64 + cb;
  *(s16x8*)&ld[nl][cb] = *(const s16x8*)src;
  *(s16x8*)&ld[nl][cb + 8] = *(const s16x8*)(src + 8);
  __syncthreads();
  const int d = t >> 2, np = (t & 3) * 16;
  short* dst = vt + (size_t)(bh * 64 + d) * 1024 + n0 + np;
  s16x8 o0, o1;
  #pragma unroll
  for (int p = 0; p < 8; ++p) { o0[p] = ld[np + p][d]; o1[p] = ld[np + 8 + p][d]; }
  *(s16x8*)dst = o0;
  *(s16x8*)(dst + 8) = o1;
}

// ---------------- flash attention (XCD-local KV + defer-max) ----------------
__launch_bounds__(256, 2)
__global__ void attn(const short* __restrict__ qb, const short* __restrict__ kb,
                     const short* __restrict__ vt, short* __restrict__ ob) {
  __shared__ short Ks[64 * 64];
  __shared__ short Vs[64 * 64];
  __shared__ short Pl[4][32 * 64];
  const int t = threadIdx.x, l = t & 63, w = t >> 6;
  const int lin = blockIdx.y * gridDim.x + blockIdx.x;
  const int xcd = lin & 7, slot = lin >> 3;
  const int bh = xcd * 8 + (slot >> 3);
  const int b = bh >> 4, h = bh & 15;
  const int q0 = (slot & 7) * 128 + w * 32;
  const short* qp = qb + (size_t)bh * (N_ * D_);
  const short* kp = kb + (size_t)bh * (N_ * D_);
  const short* vp = vt + (size_t)bh * (D_ * N_);

  s16x8 qf[2][2];
  #pragma unroll
  for (int mf = 0; mf < 2; ++mf)
    #pragma unroll
    for (int kk = 0; kk < 2; ++kk)
      qf[mf][kk] = *(const s16x8*)&qp[(q0 + mf * 16 + (l & 15)) * 64 + kk * 32 + ((l >> 4) * 8)];

  f32x4 aco[2][4];
  float rm[2][4], rl[2][4];
  const f32x4 z4 = {0.f, 0.f, 0.f, 0.f};
  #pragma unroll
  for (int mf = 0; mf < 2; ++mf) {
    #pragma unroll
    for (int nd = 0; nd < 4; ++nd) aco[mf][nd] = z4;
    #pragma unroll
    for (int i = 0; i < 4; ++i) { rm[mf][i] = -1e30f; rl[mf][i] = 0.f; }
  }

  const int sr = t >> 2, sc = (t & 3) * 2;
  s16x8 rk[2], rv[2];
  #pragma unroll
  for (int p = 0; p < 2; ++p) {
    rk[p] = *(const s16x8*)&kp[sr * 64 + (sc + p) * 8];
    rv[p] = *(const s16x8*)&vp[sr * 1024 + (sc + p) * 8];
  }

  for (int kt = 0; kt < 16; ++kt) {
    if (kt) __syncthreads();
    #pragma unroll
    for (int p = 0; p < 2; ++p) {
      const int cs = ((sc + p) ^ (sr & 7)) << 3;
      *(s16x8*)&Ks[sr * 64 + cs] = rk[p];
      *(s16x8*)&Vs[sr * 64 + cs] = rv[p];
    }
    __syncthreads();
    if (kt < 15) {
      const int kv0 = (kt + 1) * 64;
      #pragma unroll
      for (int p = 0; p < 2; ++p) {
        rk[p] = *(const s16x8*)&kp[(kv0 + sr) * 64 + (sc + p) * 8];
        rv[p] = *(const s16x8*)&vp[sr * 1024 + kv0 + (sc + p) * 8];
      }
    }

    f32x4 s[2][4];
    #pragma unroll
    for (int mf = 0; mf < 2; ++mf)
      #pragma unroll
      for (int nf = 0; nf < 4; ++nf) s[mf][nf] = z4;

    #pragma unroll
    for (int kk = 0; kk < 2; ++kk) {
      const int c16 = kk * 4 + (l >> 4);
      s16x8 kf[4];
      #pragma unroll
      for (int nf = 0; nf < 4; ++nf) {
        const int r = nf * 16 + (l & 15);
        kf[nf] = *(const s16x8*)&Ks[r * 64 + ((c16 ^ (r & 7)) << 3)];
      }
      __builtin_amdgcn_s_setprio(1);
      #pragma unroll
      for (int mf = 0; mf < 2; ++mf)
        #pragma unroll
        for (int nf = 0; nf < 4; ++nf)
          s[mf][nf] = __builtin_amdgcn_mfma_f32_16x16x32_bf16(qf[mf][kk], kf[nf], s[mf][nf], 0, 0, 0);
      __builtin_amdgcn_s_setprio(0);
    }

    #pragma unroll
    for (int mf = 0; mf < 2; ++mf) {
      #pragma unroll
      for (int i = 0; i < 4; ++i) {
        float pm = fmaxf(fmaxf(s[mf][0][i], s[mf][1][i]), fmaxf(s[mf][2][i], s[mf][3][i]));
        pm = fmaxf(pm, __shfl_xor(pm, 1));
        pm = fmaxf(pm, __shfl_xor(pm, 2));
        pm = fmaxf(pm, __shfl_xor(pm, 4));
        pm = fmaxf(pm, __shfl_xor(pm, 8));
        if (!__all(pm - rm[mf][i] <= 8.f)) {
          const float nm = fmaxf(rm[mf][i], pm);
          const float corr = __expf(rm[mf][i] - nm);
          rm[mf][i] = nm;
          rl[mf][i] *= corr;
          #pragma unroll
          for (int nd = 0; nd < 4; ++nd) aco[mf][nd][i] *= corr;
        }
        float rs = 0.f;
        #pragma unroll
        for (int nf = 0; nf < 4; ++nf) {
          const float p = __expf(s[mf][nf][i] - rm[mf][i]);
          s[mf][nf][i] = p;
          rs += p;
        }
        rs += __shfl_xor(rs, 1);
        rs += __shfl_xor(rs, 2);
        rs += __shfl_xor(rs, 4);
        rs += __shfl_xor(rs, 8);
        rl[mf][i] += rs;
      }
    }

    short* pw = &Pl[w][0];
    #pragma unroll
    for (int mf = 0; mf < 2; ++mf)
      #pragma unroll
      for (int nf = 0; nf < 4; ++nf)
        #pragma unroll
        for (int i = 0; i < 4; ++i) {
          const int row = mf * 16 + ((l >> 4) << 2) + i;
          const int col = nf * 16 + (l & 15);
          pw[row * 64 + (((col >> 3) ^ (row & 7)) << 3) + (col & 7)] = f2bf(s[mf][nf][i]);
        }

    #pragma unroll
    for (int kk = 0; kk < 2; ++kk) {
      const int c16 = kk * 4 + (l >> 4);
      s16x8 vf[4];
      #pragma unroll
      for (int nd = 0; nd < 4; ++nd) {
        const int r = nd * 16 + (l & 15);
        vf[nd] = *(const s16x8*)&Vs[r * 64 + ((c16 ^ (r & 7)) << 3)];
      }
      __builtin_amdgcn_s_setprio(1);
      #pragma unroll
      for (int mf = 0; mf < 2; ++mf) {
        const int pr = mf * 16 + (l & 15);
        const s16x8 pf = *(const s16x8*)&pw[pr * 64 + ((c16 ^ (pr & 7)) << 3)];
        #pragma unroll
        for (int nd = 0; nd < 4; ++nd)
          aco[mf][nd] = __builtin_amdgcn_mfma_f32_16x16x32_bf16(pf, vf[nd], aco[mf][nd], 0, 0, 0);
      }
      __builtin_amdgcn_s_setprio(0);
    }
  }

  #pragma unroll
  for (int mf = 0; mf < 2; ++mf)
    #pragma unroll
    for (int i = 0; i < 4; ++i) {
      const float inv = 1.f / rl[mf][i];
      const int row = q0 + mf * 16 + ((l >> 4) << 2) + i;
      #pragma unroll
      for (int nd = 0; nd < 4; ++nd) {
        const int col = h * 64 + nd * 16 + (l & 15);
        ob[(size_t)(b * 1024 + row) * 1024 + col] = f2bf(aco[mf][nd][i] * inv);
      }
    }
}

// ---------------- host launcher ----------------
extern "C" void kernel_launch(void* const* d_in, const int* in_sizes, int n_in,
                              void* d_out, int out_size, void* d_ws, size_t ws_size,
                              hipStream_t stream) {
  const float* x     = (const float*)d_in[0];
  const float* c     = (const float*)d_in[1];
  const float* n1w   = (const float*)d_in[2];
  const float* n2w   = (const float*)d_in[3];
  const float* qkvw  = (const float*)d_in[4];
  const float* qkvb  = (const float*)d_in[5];
  const float* qnw   = (const float*)d_in[6];
  const float* knw   = (const float*)d_in[7];
  const float* projw = (const float*)d_in[8];
  const float* projb = (const float*)d_in[9];
  const float* w12w  = (const float*)d_in[10];
  const float* w12b  = (const float*)d_in[11];
  const float* w3w   = (const float*)d_in[12];
  const float* w3b   = (const float*)d_in[13];
  const float* adaw  = (const float*)d_in[14];
  const float* adab  = (const float*)d_in[15];
  float* outp = (float*)d_out;

  char* ws = (char*)d_ws;
  size_t off = 0;
  auto alloc = [&](size_t bytes) { void* p = ws + off; off += (bytes + 255) & ~(size_t)255; return p; };
  short* WQKV = (short*)alloc(3072ull * 1024 * 2);
  short* WPROJ = (short*)alloc(1024ull * 1024 * 2);
  short* W12B = (short*)alloc(5460ull * 1024 * 2);
  short* W3B  = (short*)alloc(1024ull * FFP_ * 2);
  float* ADA  = (float*)alloc(4ull * 6144 * 4);
  short* H1   = (short*)alloc(4096ull * 1024 * 2);
  short* QBF  = (short*)alloc(64ull * 1024 * 64 * 2);
  short* KBF  = (short*)alloc(64ull * 1024 * 64 * 2);
  short* VROW = (short*)alloc(4096ull * 1024 * 2);
  short* VTB  = (short*)alloc(64ull * 64 * 1024 * 2);
  short* OBF  = (short*)alloc(4096ull * 1024 * 2);
  short* X1B  = (short*)alloc(4096ull * 1024 * 2);
  short* H2   = (short*)alloc(4096ull * 1024 * 2);
  short* HB   = (short*)alloc(4096ull * FFP_ * 2);

  cvt4<<<2048, 256, 0, stream>>>(qkvw, WQKV, 3072 * 1024 / 4,
                                 projw, WPROJ, 1024 * 1024 / 4,
                                 w12w, W12B, 5460 * 1024 / 4,
                                 w3w, W3B, 1024 * (FFP_ / 4));
  ada_gemm<<<6144, 64, 0, stream>>>(c, adaw, adab, ADA);
  rmsmod<<<4096, 256, 0, stream>>>(x, n1w, ADA, 0, 1024, H1);
  gemm_qkv<<<dim3(24, 32), 256, 0, stream>>>(H1, WQKV, qkvb, QBF, KBF, VROW, qnw, knw);
  v_trans<<<dim3(16, 64), 256, 0, stream>>>(VROW, VTB);
  attn<<<dim3(8, 64), 256, 0, stream>>>(QBF, KBF, VTB, OBF);
  gemm_pw<1><<<dim3(16, 32), 256, 0, stream>>>(OBF, WPROJ, 1024, projb,
      ADA + 2048, x, nullptr, X1B);
  rmsmod_b<<<4096, 256, 0, stream>>>(X1B, n2w, ADA, 3072, 4096, H2);
  gemm_w12<<<dim3(22, 32), 256, 0, stream>>>(H2, W12B, w12b, HB);
  gemm_pw<4><<<dim3(16, 32), 256, 0, stream>>>(HB, W3B, FFP_, w3b,
      ADA + 5120, nullptr, X1B, outp);
}